// Round 1
// baseline (2057.643 us; speedup 1.0000x reference)
//
#include <hip/hip_runtime.h>
#include <math.h>

#define HORIZON 15
#define PAD 7
#define CIN 48
#define C2 12
#define LAT 6
#define EPS 1e-5f
#define NREP 16   // stat replicas to spread global atomic contention

// ---------------------------------------------------------------------------
// prep: transpose weights to [ci][k][co] (lane-coalesced) + rfft trig table
// ---------------------------------------------------------------------------
__global__ void prep_kernel(const float* __restrict__ w1, const float* __restrict__ w2,
                            const float* __restrict__ w3,
                            float* __restrict__ w1t, float* __restrict__ w2t,
                            float* __restrict__ w3t, float* __restrict__ trig) {
    int idx = blockIdx.x * blockDim.x + threadIdx.x;
    const int n1 = CIN * HORIZON * CIN;   // 34560
    const int n2 = CIN * HORIZON * C2;    // 8640
    const int n3 = C2 * HORIZON * LAT;    // 1080
    if (idx < n1) {
        int co = idx % CIN; int r = idx / CIN; int k = r % HORIZON; int ci = r / HORIZON;
        w1t[idx] = w1[(co * CIN + ci) * HORIZON + k];
    } else if (idx < n1 + n2) {
        int j = idx - n1;
        int co = j % C2; int r = j / C2; int k = r % HORIZON; int ci = r / HORIZON;
        w2t[j] = w2[(co * CIN + ci) * HORIZON + k];
    } else if (idx < n1 + n2 + n3) {
        int j = idx - n1 - n2;
        int co = j % LAT; int r = j / LAT; int k = r % HORIZON; int ci = r / HORIZON;
        w3t[j] = w3[(co * C2 + ci) * HORIZON + k];
    } else if (idx < n1 + n2 + n3 + 7 * HORIZON) {
        int j = idx - (n1 + n2 + n3);
        int l = j % HORIZON; int f = j / HORIZON + 1;   // freqs 1..7
        double ang = -2.0 * 3.14159265358979323846 * (double)(f * l) / 15.0;
        trig[j * 2]     = (float)cos(ang);
        trig[j * 2 + 1] = (float)sin(ang);
    }
}

// ---------------------------------------------------------------------------
// conv: thread = (sample, co). acc[15] in regs, 169 unrolled FMAs per ci.
// NCL=true: input is [B][ci][t] (raw x). NCL=false: input is [B][t][ci].
// Output written [B][l][CO]. Accumulates per-co sum/sumsq for BatchNorm.
// ---------------------------------------------------------------------------
template <int CI, int CO, bool NCL>
__global__ __launch_bounds__(256) void conv_kernel(const float* __restrict__ xin,
                                                   const float* __restrict__ wt,
                                                   float* __restrict__ yout,
                                                   float* __restrict__ stats) {
    __shared__ float s_sum[CO];
    __shared__ float s_sq[CO];
    int t = threadIdx.x;
    if (t < CO) { s_sum[t] = 0.f; s_sq[t] = 0.f; }
    __syncthreads();

    int id = blockIdx.x * 256 + t;
    int co = id % CO;
    long b = id / CO;
    const float* xr = xin + b * (long)(CI * HORIZON);

    float acc[HORIZON];
#pragma unroll
    for (int l = 0; l < HORIZON; l++) acc[l] = 0.f;

    for (int ci = 0; ci < CI; ci++) {
        float xv[HORIZON];
#pragma unroll
        for (int tt = 0; tt < HORIZON; tt++)
            xv[tt] = NCL ? xr[ci * HORIZON + tt] : xr[tt * CI + ci];
        float wv[HORIZON];
#pragma unroll
        for (int k = 0; k < HORIZON; k++)
            wv[k] = wt[(ci * HORIZON + k) * CO + co];
#pragma unroll
        for (int tt = 0; tt < HORIZON; tt++) {
            const int lo = (tt - PAD) > 0 ? (tt - PAD) : 0;
            const int hi = (tt + PAD) < (HORIZON - 1) ? (tt + PAD) : (HORIZON - 1);
#pragma unroll
            for (int l = lo; l <= hi; l++)
                acc[l] = fmaf(xv[tt], wv[tt - l + PAD], acc[l]);
        }
    }

    float s1 = 0.f, s2 = 0.f;
#pragma unroll
    for (int l = 0; l < HORIZON; l++) { s1 += acc[l]; s2 = fmaf(acc[l], acc[l], s2); }
    atomicAdd(&s_sum[co], s1);
    atomicAdd(&s_sq[co], s2);

    float* yr = yout + b * (long)(HORIZON * CO);
#pragma unroll
    for (int l = 0; l < HORIZON; l++) yr[l * CO + co] = acc[l];

    __syncthreads();
    float* st = stats + (blockIdx.x & (NREP - 1)) * 2 * CO;
    if (t < CO) {
        atomicAdd(&st[t], s_sum[t]);
        atomicAdd(&st[CO + t], s_sq[t]);
    }
}

// ---------------------------------------------------------------------------
// finalize BN: scale/shift per channel from replicated sum/sumsq
// ---------------------------------------------------------------------------
__global__ void finalize_bn(const float* __restrict__ stats, const float* __restrict__ g,
                            const float* __restrict__ be, float* __restrict__ bn,
                            int C, float invN) {
    int c = threadIdx.x;
    if (c >= C) return;
    float s1 = 0.f, s2 = 0.f;
    for (int r = 0; r < NREP; r++) { s1 += stats[r * 2 * C + c]; s2 += stats[r * 2 * C + C + c]; }
    float m   = s1 * invN;
    float var = s2 * invN - m * m;
    float sc  = g[c] * rsqrtf(var + EPS);
    bn[c * 2]     = sc;
    bn[c * 2 + 1] = fmaf(-m, sc, be[c]);
}

// ---------------------------------------------------------------------------
// in-place BN + ELU, float4 vectorized ([B][l][C] layout, C % 4 == 0)
// ---------------------------------------------------------------------------
__global__ void bn_elu_kernel(float* __restrict__ y, const float* __restrict__ bn,
                              int C, long n4) {
    long i = (long)blockIdx.x * 256 + threadIdx.x;
    if (i >= n4) return;
    float4 v = ((float4*)y)[i];
    int c0 = (int)((i * 4) % C);
    float sc, sh, h;
    sc = bn[c0 * 2]; sh = bn[c0 * 2 + 1];
    h = fmaf(v.x, sc, sh); v.x = h > 0.f ? h : expm1f(h);
    sc = bn[(c0 + 1) * 2]; sh = bn[(c0 + 1) * 2 + 1];
    h = fmaf(v.y, sc, sh); v.y = h > 0.f ? h : expm1f(h);
    sc = bn[(c0 + 2) * 2]; sh = bn[(c0 + 2) * 2 + 1];
    h = fmaf(v.z, sc, sh); v.z = h > 0.f ? h : expm1f(h);
    sc = bn[(c0 + 3) * 2]; sh = bn[(c0 + 3) * 2 + 1];
    h = fmaf(v.w, sc, sh); v.w = h > 0.f ? h : expm1f(h);
    ((float4*)y)[i] = v;
}

// ---------------------------------------------------------------------------
// tail: conv3 (+b3) -> rfft power stats (f, a, b_off) + phase linear v
// thread = (sample, co in 0..5); y3 row stays in registers
// ---------------------------------------------------------------------------
__global__ __launch_bounds__(256) void tail_kernel(const float* __restrict__ h2,
                                                   const float* __restrict__ w3t,
                                                   const float* __restrict__ b3,
                                                   const float* __restrict__ pw,
                                                   const float* __restrict__ trig,
                                                   float* __restrict__ out,
                                                   float* __restrict__ vout,
                                                   float* __restrict__ stats) {
    __shared__ float s_sum[2 * LAT];
    __shared__ float s_sq[2 * LAT];
    int t = threadIdx.x;
    if (t < 2 * LAT) { s_sum[t] = 0.f; s_sq[t] = 0.f; }
    __syncthreads();

    int id = blockIdx.x * 256 + t;
    int co = id % LAT;
    long b = id / LAT;
    const float* xr = h2 + b * (long)(C2 * HORIZON);

    float acc[HORIZON];
#pragma unroll
    for (int l = 0; l < HORIZON; l++) acc[l] = b3[co];

    for (int ci = 0; ci < C2; ci++) {
        float xv[HORIZON];
#pragma unroll
        for (int tt = 0; tt < HORIZON; tt++) xv[tt] = xr[tt * C2 + ci];
        float wv[HORIZON];
#pragma unroll
        for (int k = 0; k < HORIZON; k++) wv[k] = w3t[(ci * HORIZON + k) * LAT + co];
#pragma unroll
        for (int tt = 0; tt < HORIZON; tt++) {
            const int lo = (tt - PAD) > 0 ? (tt - PAD) : 0;
            const int hi = (tt + PAD) < (HORIZON - 1) ? (tt + PAD) : (HORIZON - 1);
#pragma unroll
            for (int l = lo; l <= hi; l++)
                acc[l] = fmaf(xv[tt], wv[tt - l + PAD], acc[l]);
        }
    }

    // DC bin / b_off
    float ssum = 0.f;
#pragma unroll
    for (int l = 0; l < HORIZON; l++) ssum += acc[l];
    float b_off = ssum * (1.f / 15.f);

    // bins 1..7 power
    float psum = 0.f, fnum = 0.f;
#pragma unroll
    for (int j = 0; j < 7; j++) {
        float re = 0.f, im = 0.f;
#pragma unroll
        for (int l = 0; l < HORIZON; l++) {
            float c = trig[(j * HORIZON + l) * 2];
            float s = trig[(j * HORIZON + l) * 2 + 1];
            re = fmaf(acc[l], c, re);
            im = fmaf(acc[l], s, im);
        }
        float p = fmaf(re, re, im * im);
        psum += p;
        fnum = fmaf((float)(j + 1), p, fnum);
    }
    float f = fnum / psum;
    float a = 2.f * sqrtf(psum) * (1.f / 15.f);

    float* orow = out + b * 24;
    orow[6 + co]  = f;
    orow[12 + co] = a;
    orow[18 + co] = b_off;

    // phase linear (pb dropped: cancelled by batch BN)
    float v0 = 0.f, v1 = 0.f;
#pragma unroll
    for (int l = 0; l < HORIZON; l++) {
        v0 = fmaf(acc[l], pw[(co * 2 + 0) * HORIZON + l], v0);
        v1 = fmaf(acc[l], pw[(co * 2 + 1) * HORIZON + l], v1);
    }
    vout[b * 12 + co * 2]     = v0;
    vout[b * 12 + co * 2 + 1] = v1;
    atomicAdd(&s_sum[co * 2], v0);
    atomicAdd(&s_sq[co * 2], v0 * v0);
    atomicAdd(&s_sum[co * 2 + 1], v1);
    atomicAdd(&s_sq[co * 2 + 1], v1 * v1);

    __syncthreads();
    float* st = stats + (blockIdx.x & (NREP - 1)) * 2 * (2 * LAT);
    if (t < 2 * LAT) {
        atomicAdd(&st[t], s_sum[t]);
        atomicAdd(&st[2 * LAT + t], s_sq[t]);
    }
}

// ---------------------------------------------------------------------------
// phase: BN + atan2, thread per sample
// ---------------------------------------------------------------------------
__global__ void phase_kernel(const float* __restrict__ v, const float* __restrict__ bnP,
                             float* __restrict__ out, long B) {
    long b = (long)blockIdx.x * 256 + threadIdx.x;
    if (b >= B) return;
#pragma unroll
    for (int co = 0; co < LAT; co++) {
        float v0 = v[b * 12 + co * 2];
        float v1 = v[b * 12 + co * 2 + 1];
        int c0 = co * 2, c1 = co * 2 + 1;
        v0 = fmaf(v0, bnP[c0 * 2], bnP[c0 * 2 + 1]);
        v1 = fmaf(v1, bnP[c1 * 2], bnP[c1 * 2 + 1]);
        out[b * 24 + co] = atan2f(v1, v0) * 0.15915494309189535f; // 1/(2*pi)
    }
}

// ---------------------------------------------------------------------------
extern "C" void kernel_launch(void* const* d_in, const int* in_sizes, int n_in,
                              void* d_out, int out_size, void* d_ws, size_t ws_size,
                              hipStream_t stream) {
    const float* x   = (const float*)d_in[0];
    const float* w1  = (const float*)d_in[1];
    const float* g1  = (const float*)d_in[3];
    const float* be1 = (const float*)d_in[4];
    const float* w2  = (const float*)d_in[5];
    const float* g2  = (const float*)d_in[7];
    const float* be2 = (const float*)d_in[8];
    const float* w3  = (const float*)d_in[9];
    const float* b3  = (const float*)d_in[10];
    const float* pw  = (const float*)d_in[11];
    const float* pg  = (const float*)d_in[13];
    const float* pbe = (const float*)d_in[14];
    float* out = (float*)d_out;

    long B = (long)in_sizes[0] / (CIN * HORIZON);

    float* ws = (float*)d_ws;
    float* y1 = ws;                       // B*720
    float* y2 = y1 + B * 720;             // B*180
    float* vv = y2 + B * 180;             // B*12
    float* stats1 = vv + B * 12;          // NREP*96
    float* stats2 = stats1 + NREP * 96;   // NREP*24
    float* statsP = stats2 + NREP * 24;   // NREP*24
    float* bn1 = statsP + NREP * 24;      // 96
    float* bn2 = bn1 + 96;                // 24
    float* bnP = bn2 + 24;                // 24
    float* w1t = bnP + 24;                // 34560
    float* w2t = w1t + CIN * HORIZON * CIN;   // 8640
    float* w3t = w2t + CIN * HORIZON * C2;    // 1080
    float* trig = w3t + C2 * HORIZON * LAT;   // 210

    // zero all stat replicas
    hipMemsetAsync(stats1, 0, NREP * (96 + 24 + 24) * sizeof(float), stream);

    const int prep_total = CIN*HORIZON*CIN + CIN*HORIZON*C2 + C2*HORIZON*LAT + 7*HORIZON;
    prep_kernel<<<(prep_total + 255) / 256, 256, 0, stream>>>(w1, w2, w3, w1t, w2t, w3t, trig);

    // conv1: B*48 threads
    conv_kernel<CIN, CIN, true><<<(int)(B * CIN / 256), 256, 0, stream>>>(x, w1t, y1, stats1);
    finalize_bn<<<1, 64, 0, stream>>>(stats1, g1, be1, bn1, CIN, 1.f / (float)(B * HORIZON));
    bn_elu_kernel<<<(int)(B * 720 / 4 / 256), 256, 0, stream>>>(y1, bn1, CIN, B * 720 / 4);

    // conv2: B*12 threads
    conv_kernel<CIN, C2, false><<<(int)(B * C2 / 256), 256, 0, stream>>>(y1, w2t, y2, stats2);
    finalize_bn<<<1, 64, 0, stream>>>(stats2, g2, be2, bn2, C2, 1.f / (float)(B * HORIZON));
    bn_elu_kernel<<<(int)(B * 180 / 4 / 256), 256, 0, stream>>>(y2, bn2, C2, B * 180 / 4);

    // tail: conv3 + fft stats + phase linear; B*6 threads
    tail_kernel<<<(int)(B * LAT / 256), 256, 0, stream>>>(y2, w3t, b3, pw, trig, out, vv, statsP);
    finalize_bn<<<1, 64, 0, stream>>>(statsP, pg, pbe, bnP, 2 * LAT, 1.f / (float)B);

    phase_kernel<<<(int)((B + 255) / 256), 256, 0, stream>>>(vv, bnP, out, B);
}

// Round 4
// 772.401 us; speedup vs baseline: 2.6640x; 2.6640x over previous
//
#include <hip/hip_runtime.h>
#include <math.h>

#define HORIZON 15
#define PAD 7
#define CIN 48
#define C2 12
#define LAT 6
#define EPS 1e-5f
#define NREP 16

typedef __bf16 bf16x8 __attribute__((ext_vector_type(8)));
typedef float f32x4 __attribute__((ext_vector_type(4)));
typedef unsigned short ushort8v __attribute__((ext_vector_type(8)));
typedef unsigned short ushortT;

// bf16 split: v ~= hi + lo with hi = bf16(v), lo = bf16(v - hi)
__device__ inline void bfsplit(float v, ushortT& h, ushortT& l) {
    __bf16 bh = (__bf16)v;
    float fh = (float)bh;
    __bf16 bl = (__bf16)(v - fh);
    h = __builtin_bit_cast(ushortT, bh);
    l = __builtin_bit_cast(ushortT, bl);
}

// ---------------------------------------------------------------------------
// prep: dense banded split weight matrices (n-major, k-contiguous, padded),
// w3t for tail, rfft trig table.
// W1: [768][736]  n = l*48+co (<720), k = ci*15+t (<720)
// W2: [192][736]  n = l*12+co (<180), k = t*48+ci (<720)
// ---------------------------------------------------------------------------
__global__ void prep_kernel(const float* __restrict__ w1, const float* __restrict__ w2,
                            const float* __restrict__ w3,
                            ushortT* __restrict__ w1h, ushortT* __restrict__ w1l,
                            ushortT* __restrict__ w2h, ushortT* __restrict__ w2l,
                            float* __restrict__ w3t, float* __restrict__ trig) {
    int idx = blockIdx.x * blockDim.x + threadIdx.x;
    const int n1 = 768 * 736;
    const int n2 = 192 * 736;
    const int n3 = C2 * HORIZON * LAT;
    if (idx < n1) {
        int n = idx / 736, k = idx % 736;
        float v = 0.f;
        if (n < 720 && k < 720) {
            int l = n / 48, co = n % 48, ci = k / 15, t = k % 15;
            int d = t - l;
            if (d >= -PAD && d <= PAD) v = w1[(co * CIN + ci) * HORIZON + (d + PAD)];
        }
        ushortT h, lo; bfsplit(v, h, lo);
        w1h[idx] = h; w1l[idx] = lo;
    } else if (idx < n1 + n2) {
        int j = idx - n1;
        int n = j / 736, k = j % 736;
        float v = 0.f;
        if (n < 180 && k < 720) {
            int l = n / 12, co = n % 12, t = k / 48, ci = k % 48;
            int d = t - l;
            if (d >= -PAD && d <= PAD) v = w2[(co * CIN + ci) * HORIZON + (d + PAD)];
        }
        ushortT h, lo; bfsplit(v, h, lo);
        w2h[j] = h; w2l[j] = lo;
    } else if (idx < n1 + n2 + n3) {
        int j = idx - n1 - n2;
        int co = j % LAT; int r = j / LAT; int k = r % HORIZON; int ci = r / HORIZON;
        w3t[j] = w3[(co * C2 + ci) * HORIZON + k];
    } else if (idx < n1 + n2 + n3 + 7 * HORIZON) {
        int j = idx - (n1 + n2 + n3);
        int l = j % HORIZON; int f = j / HORIZON + 1;
        double ang = -2.0 * 3.14159265358979323846 * (double)(f * l) / 15.0;
        trig[j * 2]     = (float)cos(ang);
        trig[j * 2 + 1] = (float)sin(ang);
    }
}

// ---------------------------------------------------------------------------
// Split-precision bf16 MFMA GEMM: Y[M][nreal] = A[M][Ka] * W[n][k]^T
// acc = Ah*Bh + Al*Bh + Ah*Bl  (fp32-fidelity)
// Tile: BM=128, BN=NFRAG*16, BK=32; 4 waves, each 32 rows x BN cols.
// LDS layout frag-contiguous: 16-row block blk: offset blk*1024B + lane*16B,
// lane = (row%16) + 16*(k_local/8) -> matches MFMA A/B fragment directly.
// Stats layout PLANAR: s_stats[c] = sum, s_stats[CSTAT+c] = sumsq
// (round-2/3 NaN root cause: interleaved here vs planar in finalize_bn).
// ---------------------------------------------------------------------------
template <int NFRAG, int CSTAT, bool FUSE_BN>
__global__ __launch_bounds__(256, 2)
void gemm_split(const float* __restrict__ A, int Ka,
                const ushortT* __restrict__ Bh, const ushortT* __restrict__ Bl,
                const float* __restrict__ bnp,
                float* __restrict__ Y, int ldy, int nreal,
                float* __restrict__ stats) {
    constexpr int NB = (NFRAG == 15) ? 16 : 12;   // staged 16-row n-blocks
    __shared__ ushortT s_ah[8 * 512];
    __shared__ ushortT s_al[8 * 512];
    __shared__ ushortT s_bh[NB * 512];
    __shared__ ushortT s_bl[NB * 512];
    __shared__ float s_stats[2 * CSTAT];

    const int tid = threadIdx.x;
    const int w = tid >> 6, lane = tid & 63;
    const int lr = lane & 15, lq = lane >> 4;
    if (tid < 2 * CSTAT) s_stats[tid] = 0.f;

    const long m_base = (long)blockIdx.x * 128;
    const int n0 = blockIdx.y * (NFRAG * 16);

    f32x4 acc[2][NFRAG];
#pragma unroll
    for (int i = 0; i < 2; i++)
#pragma unroll
        for (int j = 0; j < NFRAG; j++) acc[i][j] = (f32x4){0.f, 0.f, 0.f, 0.f};

    const int KSTEPS = 736 / 32;
    for (int ks = 0; ks < KSTEPS; ks++) {
        const int k0 = ks * 32;
        __syncthreads();

        // ---- stage B (both splits): 16B vector load -> LDS store ----
#pragma unroll
        for (int j = 0; j < NB / 4; j++) {
            int nb = w * (NB / 4) + j;
            long grow = (long)(n0 + nb * 16 + lr) * 736 + k0 + lq * 8;
            ushort8v bvh = *(const ushort8v*)(Bh + grow);
            ushort8v bvl = *(const ushort8v*)(Bl + grow);
            *(ushort8v*)(s_bh + nb * 512 + lane * 8) = bvh;
            *(ushort8v*)(s_bl + nb * 512 + lane * 8) = bvl;
        }

        // ---- stage A: f32 load -> (optional BN+ELU) -> split -> LDS ----
#pragma unroll
        for (int j = 0; j < 2; j++) {
            int fb = w * 2 + j;
            long m = m_base + fb * 16 + lr;
            int k = k0 + lq * 8;
            ushort8v vh = (ushort8v)0, vl = (ushort8v)0;
            if (k < Ka) {
                const float4* p = (const float4*)(A + m * (long)Ka + k);
                float4 u0 = p[0], u1 = p[1];
                float f[8] = {u0.x, u0.y, u0.z, u0.w, u1.x, u1.y, u1.z, u1.w};
#pragma unroll
                for (int jj = 0; jj < 8; jj++) {
                    float v = f[jj];
                    if (FUSE_BN) {
                        int c = (k + jj) % 48;
                        float h = fmaf(v, bnp[c * 2], bnp[c * 2 + 1]);
                        v = h > 0.f ? h : expm1f(h);
                    }
                    ushortT hh, ll; bfsplit(v, hh, ll);
                    vh[jj] = hh; vl[jj] = ll;
                }
            }
            *(ushort8v*)(s_ah + fb * 512 + lane * 8) = vh;
            *(ushort8v*)(s_al + fb * 512 + lane * 8) = vl;
        }

        __syncthreads();

        // ---- fragments + MFMA ----
        bf16x8 ah[2], al[2];
#pragma unroll
        for (int fr = 0; fr < 2; fr++) {
            ah[fr] = *(const bf16x8*)(s_ah + (w * 2 + fr) * 512 + lane * 8);
            al[fr] = *(const bf16x8*)(s_al + (w * 2 + fr) * 512 + lane * 8);
        }
#pragma unroll
        for (int fc = 0; fc < NFRAG; fc++) {
            bf16x8 bhf = *(const bf16x8*)(s_bh + fc * 512 + lane * 8);
            bf16x8 blf = *(const bf16x8*)(s_bl + fc * 512 + lane * 8);
#pragma unroll
            for (int fr = 0; fr < 2; fr++) {
                acc[fr][fc] = __builtin_amdgcn_mfma_f32_16x16x32_bf16(ah[fr], bhf, acc[fr][fc], 0, 0, 0);
                acc[fr][fc] = __builtin_amdgcn_mfma_f32_16x16x32_bf16(al[fr], bhf, acc[fr][fc], 0, 0, 0);
                acc[fr][fc] = __builtin_amdgcn_mfma_f32_16x16x32_bf16(ah[fr], blf, acc[fr][fc], 0, 0, 0);
            }
        }
    }

    // ---- epilogue: store + per-channel stats (PLANAR layout) ----
    // C/D layout: col = lane&15, row = (lane>>4)*4 + reg
    float ps[3] = {0.f, 0.f, 0.f}, qs[3] = {0.f, 0.f, 0.f};
#pragma unroll
    for (int fc = 0; fc < NFRAG; fc++) {
        int col = n0 + fc * 16 + lr;
        int j = fc % 3;
#pragma unroll
        for (int fr = 0; fr < 2; fr++) {
#pragma unroll
            for (int r = 0; r < 4; r++) {
                float v = acc[fr][fc][r];
                long row = m_base + w * 32 + fr * 16 + lq * 4 + r;
                if (col < nreal) Y[row * (long)ldy + col] = v;
                ps[j] += v;
                qs[j] = fmaf(v, v, qs[j]);
            }
        }
    }
#pragma unroll
    for (int j = 0; j < 3; j++) {
        int c = (lr + 16 * j) % CSTAT;
        atomicAdd(&s_stats[c], ps[j]);
        atomicAdd(&s_stats[CSTAT + c], qs[j]);
    }
    __syncthreads();
    if (tid < 2 * CSTAT)
        atomicAdd(&stats[(blockIdx.x & (NREP - 1)) * 2 * CSTAT + tid], s_stats[tid]);
}

// ---------------------------------------------------------------------------
// finalize BN: planar stats [sum[0..C-1], sumsq[0..C-1]] per replica
// ---------------------------------------------------------------------------
__global__ void finalize_bn(const float* __restrict__ stats, const float* __restrict__ g,
                            const float* __restrict__ be, float* __restrict__ bn,
                            int C, float invN) {
    int c = threadIdx.x;
    if (c >= C) return;
    float s1 = 0.f, s2 = 0.f;
    for (int r = 0; r < NREP; r++) { s1 += stats[r * 2 * C + c]; s2 += stats[r * 2 * C + C + c]; }
    float m   = s1 * invN;
    float var = s2 * invN - m * m;
    float sc  = g[c] * rsqrtf(var + EPS);
    bn[c * 2]     = sc;
    bn[c * 2 + 1] = fmaf(-m, sc, be[c]);
}

// ---------------------------------------------------------------------------
// tail: BN2+ELU fused on load -> conv3 (+b3) -> rfft stats + phase linear
// ---------------------------------------------------------------------------
__global__ __launch_bounds__(256) void tail_kernel(const float* __restrict__ h2,
                                                   const float* __restrict__ w3t,
                                                   const float* __restrict__ b3,
                                                   const float* __restrict__ pw,
                                                   const float* __restrict__ trig,
                                                   const float* __restrict__ bn2,
                                                   float* __restrict__ out,
                                                   float* __restrict__ vout,
                                                   float* __restrict__ stats) {
    __shared__ float s_sum[2 * LAT];
    __shared__ float s_sq[2 * LAT];
    int t = threadIdx.x;
    if (t < 2 * LAT) { s_sum[t] = 0.f; s_sq[t] = 0.f; }
    __syncthreads();

    int id = blockIdx.x * 256 + t;
    int co = id % LAT;
    long b = id / LAT;
    const float* xr = h2 + b * (long)(C2 * HORIZON);

    float acc[HORIZON];
#pragma unroll
    for (int l = 0; l < HORIZON; l++) acc[l] = b3[co];

    for (int ci = 0; ci < C2; ci++) {
        float sc = bn2[ci * 2], sh = bn2[ci * 2 + 1];
        float xv[HORIZON];
#pragma unroll
        for (int tt = 0; tt < HORIZON; tt++) {
            float h = fmaf(xr[tt * C2 + ci], sc, sh);
            xv[tt] = h > 0.f ? h : expm1f(h);
        }
        float wv[HORIZON];
#pragma unroll
        for (int k = 0; k < HORIZON; k++) wv[k] = w3t[(ci * HORIZON + k) * LAT + co];
#pragma unroll
        for (int tt = 0; tt < HORIZON; tt++) {
            const int lo = (tt - PAD) > 0 ? (tt - PAD) : 0;
            const int hi = (tt + PAD) < (HORIZON - 1) ? (tt + PAD) : (HORIZON - 1);
#pragma unroll
            for (int l = lo; l <= hi; l++)
                acc[l] = fmaf(xv[tt], wv[tt - l + PAD], acc[l]);
        }
    }

    float ssum = 0.f;
#pragma unroll
    for (int l = 0; l < HORIZON; l++) ssum += acc[l];
    float b_off = ssum * (1.f / 15.f);

    float psum = 0.f, fnum = 0.f;
#pragma unroll
    for (int j = 0; j < 7; j++) {
        float re = 0.f, im = 0.f;
#pragma unroll
        for (int l = 0; l < HORIZON; l++) {
            float c = trig[(j * HORIZON + l) * 2];
            float s = trig[(j * HORIZON + l) * 2 + 1];
            re = fmaf(acc[l], c, re);
            im = fmaf(acc[l], s, im);
        }
        float p = fmaf(re, re, im * im);
        psum += p;
        fnum = fmaf((float)(j + 1), p, fnum);
    }
    float f = fnum / psum;
    float a = 2.f * sqrtf(psum) * (1.f / 15.f);

    float* orow = out + b * 24;
    orow[6 + co]  = f;
    orow[12 + co] = a;
    orow[18 + co] = b_off;

    float v0 = 0.f, v1 = 0.f;
#pragma unroll
    for (int l = 0; l < HORIZON; l++) {
        v0 = fmaf(acc[l], pw[(co * 2 + 0) * HORIZON + l], v0);
        v1 = fmaf(acc[l], pw[(co * 2 + 1) * HORIZON + l], v1);
    }
    vout[b * 12 + co * 2]     = v0;
    vout[b * 12 + co * 2 + 1] = v1;
    atomicAdd(&s_sum[co * 2], v0);
    atomicAdd(&s_sq[co * 2], v0 * v0);
    atomicAdd(&s_sum[co * 2 + 1], v1);
    atomicAdd(&s_sq[co * 2 + 1], v1 * v1);

    __syncthreads();
    float* st = stats + (blockIdx.x & (NREP - 1)) * 2 * (2 * LAT);
    if (t < 2 * LAT) {
        atomicAdd(&st[t], s_sum[t]);
        atomicAdd(&st[2 * LAT + t], s_sq[t]);
    }
}

// ---------------------------------------------------------------------------
__global__ void phase_kernel(const float* __restrict__ v, const float* __restrict__ bnP,
                             float* __restrict__ out, long B) {
    long b = (long)blockIdx.x * 256 + threadIdx.x;
    if (b >= B) return;
#pragma unroll
    for (int co = 0; co < LAT; co++) {
        float v0 = v[b * 12 + co * 2];
        float v1 = v[b * 12 + co * 2 + 1];
        int c0 = co * 2, c1 = co * 2 + 1;
        v0 = fmaf(v0, bnP[c0 * 2], bnP[c0 * 2 + 1]);
        v1 = fmaf(v1, bnP[c1 * 2], bnP[c1 * 2 + 1]);
        out[b * 24 + co] = atan2f(v1, v0) * 0.15915494309189535f;
    }
}

// ---------------------------------------------------------------------------
extern "C" void kernel_launch(void* const* d_in, const int* in_sizes, int n_in,
                              void* d_out, int out_size, void* d_ws, size_t ws_size,
                              hipStream_t stream) {
    const float* x   = (const float*)d_in[0];
    const float* w1  = (const float*)d_in[1];
    const float* g1  = (const float*)d_in[3];
    const float* be1 = (const float*)d_in[4];
    const float* w2  = (const float*)d_in[5];
    const float* g2  = (const float*)d_in[7];
    const float* be2 = (const float*)d_in[8];
    const float* w3  = (const float*)d_in[9];
    const float* b3  = (const float*)d_in[10];
    const float* pw  = (const float*)d_in[11];
    const float* pg  = (const float*)d_in[13];
    const float* pbe = (const float*)d_in[14];
    float* out = (float*)d_out;

    long B = (long)in_sizes[0] / (CIN * HORIZON);   // 65536

    // bf16 arrays FIRST: 16B-aligned base + 1472B row stride (16B-divisible).
    ushortT* w1h = (ushortT*)d_ws;          // 768*736
    ushortT* w1l = w1h + 768 * 736;
    ushortT* w2h = w1l + 768 * 736;         // 192*736
    ushortT* w2l = w2h + 192 * 736;
    float* y1 = (float*)(w2l + 192 * 736);  // 16B-aligned
    float* y2 = y1 + B * 720;               // B*180
    float* vv = y2 + B * 180;               // B*12
    float* stats1 = vv + B * 12;            // NREP*96
    float* stats2 = stats1 + NREP * 96;     // NREP*24
    float* statsP = stats2 + NREP * 24;     // NREP*24
    float* bn1 = statsP + NREP * 24;        // 96
    float* bn2 = bn1 + 96;                  // 24
    float* bnP = bn2 + 24;                  // 24
    float* w3t = bnP + 24;                  // 1080
    float* trig = w3t + C2 * HORIZON * LAT; // 210

    hipMemsetAsync(stats1, 0, NREP * (96 + 24 + 24) * sizeof(float), stream);

    const int prep_total = 768 * 736 + 192 * 736 + C2 * HORIZON * LAT + 7 * HORIZON;
    prep_kernel<<<(prep_total + 255) / 256, 256, 0, stream>>>(w1, w2, w3, w1h, w1l, w2h, w2l, w3t, trig);

    // GEMM1: x [B][720] -> y1 [B][720], stats1
    gemm_split<15, 48, false><<<dim3((int)(B / 128), 3), 256, 0, stream>>>(
        x, 720, w1h, w1l, nullptr, y1, 720, 720, stats1);
    finalize_bn<<<1, 64, 0, stream>>>(stats1, g1, be1, bn1, CIN, 1.f / (float)(B * HORIZON));

    // GEMM2: BN1+ELU fused in A-staging; y1 -> y2 [B][180], stats2
    gemm_split<12, 12, true><<<dim3((int)(B / 128), 1), 256, 0, stream>>>(
        y1, 720, w2h, w2l, bn1, y2, 180, 180, stats2);
    finalize_bn<<<1, 64, 0, stream>>>(stats2, g2, be2, bn2, C2, 1.f / (float)(B * HORIZON));

    // tail: BN2+ELU fused on load
    tail_kernel<<<(int)(B * LAT / 256), 256, 0, stream>>>(y2, w3t, b3, pw, trig, bn2, out, vv, statsP);
    finalize_bn<<<1, 64, 0, stream>>>(statsP, pg, pbe, bnP, 2 * LAT, 1.f / (float)B);

    phase_kernel<<<(int)((B + 255) / 256), 256, 0, stream>>>(vv, bnP, out, B);
}